// Round 5
// baseline (91.069 us; speedup 1.0000x reference)
//
#include <hip/hip_runtime.h>
#include <cstddef>

#define B_ 2
#define C_ 32
#define CP 33
#define W_ 256
#define H_ 256
#define X_ 512
#define Y_ 512
#define YT 32

typedef __bf16 bf16x8 __attribute__((ext_vector_type(8)));
typedef __bf16 bf16x4 __attribute__((ext_vector_type(4)));
typedef float  f32x4  __attribute__((ext_vector_type(4)));

// ws layout:
//   wlonT bf16 [B][X][W], wlatT bf16 [B][Y][H], wt33 bf16 [B][CP][W][H],
//   eeT0 f32 [B][Y][X]

// ---------------- prep: bf16 tables ----------------
__global__ __launch_bounds__(256) void prep_kernel(
    const float* __restrict__ xin_lon, const float* __restrict__ xin_lat,
    const float* __restrict__ xout_lon, const float* __restrict__ xout_lat,
    const float* __restrict__ init_ls, const float* __restrict__ wt,
    __bf16* __restrict__ wlonT, __bf16* __restrict__ wlatT,
    __bf16* __restrict__ wt33)
{
    const int NLON = B_ * X_ * W_;
    const int NLAT = B_ * Y_ * H_;
    int t = blockIdx.x * 256 + threadIdx.x;
    float ls = init_ls[0];
    float cc = -0.5f / (ls * ls);
    if (t < NLON) {
        int b = t / (X_ * W_);
        int r = t - b * (X_ * W_);
        int x = r >> 8;
        int w = r & (W_ - 1);
        float d = xin_lon[b * W_ + w] - xout_lon[b * X_ + x];
        wlonT[t] = (__bf16)__expf(cc * d * d);
    } else if (t < NLON + NLAT) {
        int j = t - NLON;
        int b = j / (Y_ * H_);
        int r = j - b * (Y_ * H_);
        int y = r >> 8;
        int h = r & (H_ - 1);
        float d = xin_lat[b * H_ + h] - xout_lat[b * Y_ + y];
        wlatT[j] = (__bf16)__expf(cc * d * d);
    } else {
        int j = t - (NLON + NLAT);
        int o = j * 4;
        int b = o / (CP * W_ * H_);
        int r = o - b * (CP * W_ * H_);
        int co = r / (W_ * H_);
        int p = r & (W_ * H_ - 1);
        float4 v;
        bf16x4 ov;
        if (co == 0) {
            v = *(const float4*)&wt[((size_t)b * C_) * (W_ * H_) + p];
            ov[0] = (__bf16)((v.x != v.x) ? 0.f : 1.f);
            ov[1] = (__bf16)((v.y != v.y) ? 0.f : 1.f);
            ov[2] = (__bf16)((v.z != v.z) ? 0.f : 1.f);
            ov[3] = (__bf16)((v.w != v.w) ? 0.f : 1.f);
        } else {
            v = *(const float4*)&wt[((size_t)b * C_ + (co - 1)) * (W_ * H_) + p];
            ov[0] = (__bf16)((v.x != v.x) ? 0.f : v.x);
            ov[1] = (__bf16)((v.y != v.y) ? 0.f : v.y);
            ov[2] = (__bf16)((v.z != v.z) ? 0.f : v.z);
            ov[3] = (__bf16)((v.w != v.w) ? 0.f : v.w);
        }
        *(bf16x4*)&wt33[o] = ov;
    }
}

// ---------------- fused two-stage MFMA contraction ----------------
// stage1: U[w=256][y=32]   = sum_h wt33[ch][w][h] * wlatT[y][h]
// stage2: ee[x-chunk][y=32]= sum_w wlonT[x][w]   * U[w][y]
// 4-slot ring, prefetch distance 3 (distance MUST be < ring depth — the
// round-4 bug was depth 3 / distance 3, which aliases the consumed slot).
template<int NXQ, bool DENS>
__global__ __launch_bounds__(256, 2) void conv_mfma(
    const __bf16* __restrict__ wt33, const __bf16* __restrict__ wlonT,
    const __bf16* __restrict__ wlatT, float* __restrict__ eeT0,
    float* __restrict__ out)
{
    constexpr int XCH = X_ / NXQ;    // x per block
    constexpr int MT  = XCH / 64;    // stage-2 m-fragments per wave

    __shared__ __bf16 Blat[8192];
    __shared__ __bf16 Ut[8192];

    int b, ch, yt, xq;
    if (DENS) {
        b  = blockIdx.x / (16 * NXQ);
        int r = blockIdx.x - b * (16 * NXQ);
        yt = r / NXQ;
        xq = r - yt * NXQ;
        ch = 0;
    } else {
        // all (yt,xq) tiles of one (b,ch) share an XCD; wt panel L2-resident
        int xcd = blockIdx.x & 7;
        int k   = blockIdx.x >> 3;   // 0..255
        int g   = k >> 5;            // 0..7
        int r   = k & 31;
        yt = r >> 1;
        xq = r & 1;
        int bc  = xcd * 8 + g;
        b  = bc >> 5;
        ch = (bc & 31) + 1;
    }
    const int y0   = yt * YT;
    const int t    = threadIdx.x;
    const int lane = t & 63;
    const int wave = t >> 6;
    const int lrow = lane & 15;
    const int lkg  = lane >> 4;

    // ---- stage wlatT y-tile into LDS (fragment-linear) ----
    {
        const __bf16* src = wlatT + ((size_t)b * Y_ + y0) * H_;
        int i = t;
#pragma unroll
        for (int it = 0; it < 4; ++it, i += 256) {
            int y = i >> 5, hc = i & 31;
            bf16x8 v = *(const bf16x8*)(src + y * H_ + hc * 8);
            int kt = hc >> 2, kg = hc & 3, nt = y >> 4;
            *(bf16x8*)&Blat[(((kt * 2 + nt) * 64) + kg * 16 + (y & 15)) * 8] = v;
        }
    }
    __syncthreads();

    // ---- stage 1: 4-slot ring, distance-3 prefetch ----
    const __bf16* wtc = wt33 + ((size_t)b * CP + ch) * (W_ * H_);
    auto loadA1 = [&](bf16x8* a, int kt) {
#pragma unroll
        for (int mt = 0; mt < 4; ++mt) {
            int w = wave * 64 + mt * 16 + lrow;
            a[mt] = *(const bf16x8*)(wtc + (size_t)w * H_ + kt * 32 + lkg * 8);
        }
    };
    f32x4 acc1[4][2] = {};
    bf16x8 r1a[4], r1b[4], r1c[4], r1d[4];
    loadA1(r1a, 0);
    loadA1(r1b, 1);
    loadA1(r1c, 2);
#pragma unroll
    for (int kt = 0; kt < 8; ++kt) {
        if (kt < 5) {
            int s = (kt + 3) & 3;
            bf16x8* an = (s == 0) ? r1a : (s == 1) ? r1b : (s == 2) ? r1c : r1d;
            loadA1(an, kt + 3);
        }
        int sc = kt & 3;
        bf16x8* ac = (sc == 0) ? r1a : (sc == 1) ? r1b : (sc == 2) ? r1c : r1d;
        bf16x8 bf[2];
#pragma unroll
        for (int nt = 0; nt < 2; ++nt)
            bf[nt] = *(const bf16x8*)&Blat[((kt * 2 + nt) * 64 + lane) * 8];
#pragma unroll
        for (int mt = 0; mt < 4; ++mt)
#pragma unroll
            for (int nt = 0; nt < 2; ++nt)
                acc1[mt][nt] = __builtin_amdgcn_mfma_f32_16x16x32_bf16(
                    ac[mt], bf[nt], acc1[mt][nt], 0, 0, 0);
    }

    // ---- issue stage-2 first 3 k-groups before publishing Ut ----
    const __bf16* lonb = wlonT + (size_t)b * X_ * W_;
    auto loadA2 = [&](bf16x8* a, int kt) {
#pragma unroll
        for (int mt = 0; mt < MT; ++mt) {
            int x = xq * XCH + wave * (XCH / 4) + mt * 16 + lrow;
            a[mt] = *(const bf16x8*)(lonb + (size_t)x * W_ + kt * 32 + lkg * 8);
        }
    };
    bf16x8 r2a[MT], r2b[MT], r2c[MT], r2d[MT];
    loadA2(r2a, 0);
    loadA2(r2b, 1);
    loadA2(r2c, 2);

    // ---- U -> LDS (stage-2 fragment-linear, transposed) ----
#pragma unroll
    for (int mt = 0; mt < 4; ++mt) {
        int w0  = wave * 64 + mt * 16 + lkg * 4;
        int kt2 = w0 >> 5;
        int kg2 = (w0 >> 3) & 3;
        int j0  = w0 & 7;
#pragma unroll
        for (int nt = 0; nt < 2; ++nt) {
            f32x4 c = acc1[mt][nt];
            bf16x4 v4;
            v4[0] = (__bf16)c[0]; v4[1] = (__bf16)c[1];
            v4[2] = (__bf16)c[2]; v4[3] = (__bf16)c[3];
            *(bf16x4*)&Ut[((kt2 * 2 + nt) * 64 + kg2 * 16 + lrow) * 8 + j0] = v4;
        }
    }
    __syncthreads();

    // ---- stage 2: 4-slot ring, distance-3 prefetch ----
    f32x4 acc2[MT][2] = {};
#pragma unroll
    for (int kt = 0; kt < 8; ++kt) {
        if (kt < 5) {
            int s = (kt + 3) & 3;
            bf16x8* an = (s == 0) ? r2a : (s == 1) ? r2b : (s == 2) ? r2c : r2d;
            loadA2(an, kt + 3);
        }
        int sc = kt & 3;
        bf16x8* ac = (sc == 0) ? r2a : (sc == 1) ? r2b : (sc == 2) ? r2c : r2d;
        bf16x8 bf[2];
#pragma unroll
        for (int nt = 0; nt < 2; ++nt)
            bf[nt] = *(const bf16x8*)&Ut[((kt * 2 + nt) * 64 + lane) * 8];
#pragma unroll
        for (int mt = 0; mt < MT; ++mt)
#pragma unroll
            for (int nt = 0; nt < 2; ++nt)
                acc2[mt][nt] = __builtin_amdgcn_mfma_f32_16x16x32_bf16(
                    ac[mt], bf[nt], acc2[mt][nt], 0, 0, 0);
    }

    // ---- epilogue ----
    float* outc = out + ((size_t)b * CP + ch) * (size_t)(X_ * Y_);
#pragma unroll
    for (int mt = 0; mt < MT; ++mt) {
        int xb = xq * XCH + wave * (XCH / 4) + mt * 16 + lkg * 4;
#pragma unroll
        for (int nt = 0; nt < 2; ++nt) {
            int y = y0 + nt * 16 + lrow;
            f32x4 c = acc2[mt][nt];
            if (DENS) {
                *(f32x4*)&eeT0[((size_t)b * Y_ + y) * X_ + xb] = c;
#pragma unroll
                for (int r = 0; r < 4; ++r)
                    outc[(size_t)(xb + r) * Y_ + y] = c[r];
            } else {
                f32x4 e = *(const f32x4*)&eeT0[((size_t)b * Y_ + y) * X_ + xb];
#pragma unroll
                for (int r = 0; r < 4; ++r) {
                    float dcl = fminf(fmaxf(e[r], 1e-6f), 1e5f);
                    outc[(size_t)(xb + r) * Y_ + y] = c[r] / dcl;
                }
            }
        }
    }
}

extern "C" void kernel_launch(void* const* d_in, const int* in_sizes, int n_in,
                              void* d_out, int out_size, void* d_ws, size_t ws_size,
                              hipStream_t stream)
{
    const float* xin_lon  = (const float*)d_in[0];
    const float* xin_lat  = (const float*)d_in[1];
    const float* wt       = (const float*)d_in[2];
    const float* xout_lon = (const float*)d_in[3];
    const float* xout_lat = (const float*)d_in[4];
    const float* init_ls  = (const float*)d_in[5];
    float* out = (float*)d_out;

    __bf16* wlonT = (__bf16*)d_ws;
    __bf16* wlatT = wlonT + (size_t)B_ * X_ * W_;
    __bf16* wt33  = wlatT + (size_t)B_ * Y_ * H_;
    float*  eeT0  = (float*)(wt33 + (size_t)B_ * CP * W_ * H_);

    prep_kernel<<<6272, 256, 0, stream>>>(xin_lon, xin_lat, xout_lon, xout_lat,
                                          init_ls, wt, wlonT, wlatT, wt33);
    conv_mfma<4, true ><<<B_ * 16 * 4, 256, 0, stream>>>(wt33, wlonT, wlatT, eeT0, out);
    conv_mfma<2, false><<<2048,        256, 0, stream>>>(wt33, wlonT, wlatT, eeT0, out);
}